// Round 1
// 353.131 us; speedup vs baseline: 1.0564x; 1.0564x over previous
//
#include <hip/hip_runtime.h>

// Event voxelization: events [N,4] f32 (x,y,t,p) -> vox[2*16*260*346] set-to-1.
//
// R1-R6: any random per-event fabric access costs ~32-40 B. R3 (183 us) = that
//        roofline; cache hints / atomics / target size all no-ops.
// R7-R12: radix partition into per-bucket segments + LDS-flag build:
//        kernel sum ~115 us (total carries ~260 us fixed harness ws-poison fills).
// R13:   partition latency attack: 512-thr WGs (24 waves/CU vs 12, LDS-capped),
//        software-pipelined phase A (prefetch next 4-group + remainder before
//        depositing current -> loads in flight during LDS atomic chain),
//        zero-bounds-check fast path for the 1077 full chunks. Build stream
//        also pipelined (prefetch next uint4 across the 8 LDS flag writes).

#define CBINS 16
#define HDIM  260
#define WDIM  346
#define NVOX  (2 * CBINS * HDIM * WDIM)   // 2,878,720
#define NBUCK 256
#define RGN   11264                        // voxels/bucket; 256*11264 >= NVOX; < 2^16
#define CHUNK 14848                        // events per pass-1 WG (29/thread at 512 thr)
#define LCAP  96                           // slab capacity per bucket (u16)
#define SENT  0xFFFFFFFFu
#define PT    512                          // partition block size

typedef float    fvec4 __attribute__((ext_vector_type(4)));
typedef unsigned uvec4 __attribute__((ext_vector_type(4)));

// -> (bucket<<16) | local_offset, or SENT. All idx math in fp32 (exact: <2^24).
__device__ __forceinline__ unsigned ev_to_packed(fvec4 e) {
    float t = e.z;
    if (!(t > 0.f && t <= 1.f)) return SENT;
    float bin = __builtin_ceilf(t * 16.f) - 1.f;          // [0,15]
    float bp  = (e.w > 0.f) ? (bin + 16.f) : bin;         // bin + 16*p
    float idxf = __builtin_fmaf(346.f, e.y, e.x);         // x + 346*y
    idxf = __builtin_fmaf(89960.f, bp, idxf);             // + W*H*16*(...)
    unsigned idx = (unsigned)idxf;
    unsigned b = idx / (unsigned)RGN;                     // mulhi+shift
    return (b << 16) | (idx - b * (unsigned)RGN);
}

__device__ __forceinline__ void deposit(unsigned v,
        unsigned short* slab, unsigned* cnt,
        unsigned* __restrict__ ovf, unsigned ovf_cap) {
    if (v == SENT) return;
    unsigned b = v >> 16;
    unsigned slot = atomicAdd(&cnt[b], 1u);
    if (slot < LCAP) slab[b * LCAP + slot] = (unsigned short)v;
    else {                                                // P ~ 3e-7 per bucket
        unsigned pos = atomicAdd(&ovf[0], 1u);
        if (pos < ovf_cap) ovf[1 + pos] = b * (unsigned)RGN + (v & 0xFFFFu);
    }
}

// ---------------- Pass 1: slab-partition into global bucket segments ----------------
__global__ __launch_bounds__(PT, 6) void partition_kernel(
        const fvec4* __restrict__ ev, int n,
        unsigned short* __restrict__ seg,    // [NBUCK * cap] u16 local offsets
        unsigned* __restrict__ gcur,         // [NBUCK] cursors (pre-zeroed)
        unsigned* __restrict__ ovf,          // [0]=count, [1..] u32 voxel idx
        unsigned cap, unsigned ovf_cap) {
    __shared__ unsigned short slab[NBUCK * LCAP];   // 49,152 B
    __shared__ unsigned cnt[NBUCK];                 // 1,024 B
    __shared__ unsigned sbase[NBUCK];               // 1,024 B

    const int w = blockIdx.x, tid = threadIdx.x;
    const int wave = tid >> 6, lane = tid & 63;
    const int base = w * CHUNK;
    const int nev = min(CHUNK, n - base);

    if (tid < NBUCK) cnt[tid] = 0;
    __syncthreads();

    if (nev == CHUNK) {
        // Fast path (1077/1078 WGs): CHUNK = 7 groups * (4*512) + 512 remainder.
        // Prefetch next group + remainder before depositing current group, so
        // HBM loads stay in flight under the LDS atomic/store chain.
        const fvec4* p = ev + base + tid;
        fvec4 c0 = __builtin_nontemporal_load(p);
        fvec4 c1 = __builtin_nontemporal_load(p + 512);
        fvec4 c2 = __builtin_nontemporal_load(p + 1024);
        fvec4 c3 = __builtin_nontemporal_load(p + 1536);
        fvec4 rem = __builtin_nontemporal_load(ev + base + 14336 + tid);
        for (int g = 0; g < 7; ++g) {
            fvec4 n0, n1, n2, n3;
            if (g < 6) {                      // uniform branch
                const fvec4* q = p + (g + 1) * 2048;
                n0 = __builtin_nontemporal_load(q);
                n1 = __builtin_nontemporal_load(q + 512);
                n2 = __builtin_nontemporal_load(q + 1024);
                n3 = __builtin_nontemporal_load(q + 1536);
            }
            deposit(ev_to_packed(c0), slab, cnt, ovf, ovf_cap);
            deposit(ev_to_packed(c1), slab, cnt, ovf, ovf_cap);
            deposit(ev_to_packed(c2), slab, cnt, ovf, ovf_cap);
            deposit(ev_to_packed(c3), slab, cnt, ovf, ovf_cap);
            if (g < 6) { c0 = n0; c1 = n1; c2 = n2; c3 = n3; }
        }
        deposit(ev_to_packed(rem), slab, cnt, ovf, ovf_cap);
    } else {
        // Tail WG (8704 events): simple guarded loop.
        for (int k = tid; k < nev; k += PT)
            deposit(ev_to_packed(__builtin_nontemporal_load(ev + base + k)),
                    slab, cnt, ovf, ovf_cap);
    }
    __syncthreads();

    // Phase B: 32-aligned global segment reservation (1 atomic per bucket).
    if (tid < NBUCK) {
        unsigned len  = min(cnt[tid], (unsigned)LCAP);
        unsigned plen = (len + 31u) & ~31u;
        sbase[tid] = atomicAdd(&gcur[tid], plen);   // cap = nchunk*LCAP -> safe
    }
    __syncthreads();

    // Phase C: wave-per-bucket aligned burst writes (pad -> sentinel RGN).
    for (int b = wave; b < NBUCK; b += PT / 64) {
        unsigned len  = min(cnt[b], (unsigned)LCAP);
        unsigned plen = (len + 31u) & ~31u;
        unsigned short* dst = seg + (size_t)b * cap + sbase[b];   // 64 B-aligned
        for (unsigned j = lane; j < plen; j += 64)
            dst[j] = (j < len) ? slab[b * LCAP + j] : (unsigned short)RGN;
    }
}

// ---------------- Pass 2: stream segment (uint4), flag in LDS, emit region ----------------
__global__ __launch_bounds__(1024) void build_kernel(
        const unsigned short* __restrict__ seg,
        const unsigned* __restrict__ gcur,
        const unsigned* __restrict__ ovf,
        fvec4* __restrict__ out, unsigned cap, unsigned ovf_cap) {
    __shared__ unsigned char flag[12288];    // RGN + sentinel zone (flag[11264..])
    const int b = blockIdx.x, tid = threadIdx.x;

    for (int i = tid; i < 12288 / 4; i += 1024) ((unsigned*)flag)[i] = 0;
    __syncthreads();

    unsigned n_b = min(gcur[b], cap);        // multiple of 32 entries (64 B)
    unsigned nq = n_b / 8;                   // uint4 = 8 u16 entries
    const uvec4* p128 = (const uvec4*)(seg + (size_t)b * cap);
    if ((unsigned)tid < nq) {
        uvec4 v = __builtin_nontemporal_load(&p128[tid]);
        unsigned j = tid;
        for (;;) {
            unsigned jn = j + 1024;
            uvec4 nx;
            bool more = jn < nq;
            if (more) nx = __builtin_nontemporal_load(&p128[jn]);  // in flight over LDS writes
            flag[v.x & 0xFFFFu] = 1; flag[v.x >> 16] = 1;
            flag[v.y & 0xFFFFu] = 1; flag[v.y >> 16] = 1;
            flag[v.z & 0xFFFFu] = 1; flag[v.z >> 16] = 1;  // sentinel -> flag[11264]
            flag[v.w & 0xFFFFu] = 1; flag[v.w >> 16] = 1;
            if (!more) break;
            v = nx; j = jn;
        }
    }
    // Fused overflow drain (normally empty: one broadcast load + skip).
    unsigned oc = min(ovf[0], ovf_cap);
    unsigned rb = (unsigned)b * RGN;
    for (unsigned j = tid; j < oc; j += 1024) {
        unsigned g = ovf[1 + j];
        if (g - rb < (unsigned)RGN) flag[g - rb] = 1;
    }
    __syncthreads();

    for (int i = tid; i < RGN / 4; i += 1024) {
        int g = b * (RGN / 4) + i;                     // float4 index
        if (g < NVOX / 4) {
            uchar4 f = ((const uchar4*)flag)[i];
            fvec4 vv = { f.x ? 1.f : 0.f, f.y ? 1.f : 0.f,
                         f.z ? 1.f : 0.f, f.w ? 1.f : 0.f };
            __builtin_nontemporal_store(vv, &out[g]);
        }
    }
}

// ---------------- Fallback (R3 path) if ws too small ----------------
__global__ __launch_bounds__(256) void scatter_flags(const fvec4* __restrict__ ev,
                                                     unsigned char* __restrict__ flags,
                                                     int n) {
    int i = blockIdx.x * blockDim.x + threadIdx.x;
    if (i >= n) return;
    fvec4 e = __builtin_nontemporal_load(&ev[i]);
    float t = e.z;
    if (t > 0.f && t <= 1.f) {
        int xi = (int)e.x, yi = (int)e.y;
        int pi = (e.w > 0.f) ? 1 : 0;
        int bin = (int)ceilf(t * (float)CBINS) - 1;
        flags[xi + WDIM * yi + WDIM * HDIM * (bin + CBINS * pi)] = 1;
    }
}
__global__ __launch_bounds__(256) void expand_flags(const uchar4* __restrict__ flags,
                                                    fvec4* __restrict__ out, int n4) {
    int i = blockIdx.x * blockDim.x + threadIdx.x;
    if (i >= n4) return;
    uchar4 f = flags[i];
    fvec4 v = { f.x ? 1.f : 0.f, f.y ? 1.f : 0.f, f.z ? 1.f : 0.f, f.w ? 1.f : 0.f };
    __builtin_nontemporal_store(v, &out[i]);
}

extern "C" void kernel_launch(void* const* d_in, const int* in_sizes, int n_in,
                              void* d_out, int out_size, void* d_ws, size_t ws_size,
                              hipStream_t stream) {
    const fvec4* ev = (const fvec4*)d_in[0];
    int n  = in_sizes[0] / 4;                // 16,000,000
    int n4 = out_size / 4;                   // 719,680
    int nchunk = (n + CHUNK - 1) / CHUNK;    // 1078

    unsigned cap = (unsigned)nchunk * LCAP;  // per-bucket segment capacity
    unsigned ovf_cap = (unsigned)n;
    size_t seg_bytes = (size_t)NBUCK * cap * sizeof(unsigned short);      // ~53 MB
    size_t cur_bytes = NBUCK * sizeof(unsigned);
    size_t ovf_bytes = (size_t)(1 + ovf_cap) * sizeof(unsigned);          // ~64 MB

    if (ws_size >= seg_bytes + cur_bytes + ovf_bytes) {
        unsigned short* seg = (unsigned short*)d_ws;
        unsigned* gcur = (unsigned*)((char*)d_ws + seg_bytes);
        unsigned* ovf  = gcur + NBUCK;       // [0]=count, entries follow
        hipMemsetAsync(gcur, 0, (NBUCK + 1) * sizeof(unsigned), stream);
        partition_kernel<<<nchunk, PT, 0, stream>>>(ev, n, seg, gcur, ovf, cap, ovf_cap);
        build_kernel<<<NBUCK, 1024, 0, stream>>>(seg, gcur, ovf, (fvec4*)d_out,
                                                 cap, ovf_cap);
    } else {
        unsigned char* flags = (unsigned char*)d_ws;
        hipMemsetAsync(flags, 0, NVOX, stream);
        scatter_flags<<<(n + 255) / 256, 256, 0, stream>>>(ev, flags, n);
        expand_flags<<<(n4 + 255) / 256, 256, 0, stream>>>((const uchar4*)flags,
                                                           (fvec4*)d_out, n4);
    }
}